// Round 9
// baseline (785.573 us; speedup 1.0000x reference)
//
#include <hip/hip_runtime.h>
#include <hip/hip_cooperative_groups.h>
#include <math.h>

namespace cg = cooperative_groups;

// ---------------------------------------------------------------------------
// TbDNet forward, round 9: cooperative fused interpreter.
//   6 dispatches total: k_prep (repack+decode), k_stem1p, k_interp (coop:
//   stem1-reduce + stem2 + 11 conv rounds with grid.sync), k_cls_pool,
//   k_fc1p, k_fc1tail (coop: fc1 reduce + fc2).
// ---------------------------------------------------------------------------

typedef __attribute__((ext_vector_type(8)))  short   short8;
typedef __attribute__((ext_vector_type(8)))  __bf16  bf16x8;
typedef __attribute__((ext_vector_type(4)))  float   f32x4;

#define NROUNDS 11
#define NKS 98          // fc1 K-splits (KC = 512)

// byte offsets in ws
#define B_WSTEM1 0UL                 // bf16 [9][128][1024]
#define B_WSTEM2 2359296UL           // bf16 [9][128][128]
#define B_WMOD   2654208UL           // 9 x bf16 [9][128][128]
#define B_WCLS   5308416UL           // bf16 [1024][128]
#define B_STEM   5570560UL           // bf16 [64][196][128]
#define B_XA     8781824UL
#define B_XB     11993088UL
#define B_FEAT   15204352UL
#define B_ATTN   18415616UL          // f32 [64][196]
#define B_SAVED  18465792UL
#define B_SCHED  18515968UL          // int [64][NROUNDS]
#define B_ACTB   18520064UL          // bf16 permuted fc1-B
#define B_FC1T   24942592UL          // f32 [1024][64]
#define B_P1X1   25204736UL          // f32 [8 slots][64][196]
// high overlays (ws ~800 MB):
#define B_S1P    67108864UL          // stem1 partials bf16 [8][64][196][128]
#define B_FC1P   100663296UL         // fc1 partials f32 [98][1024][64]

__device__ __forceinline__ unsigned short f2bf(float f) {
    unsigned int b = __float_as_uint(f);
    b += 0x7fffu + ((b >> 16) & 1u);          // RNE
    return (unsigned short)(b >> 16);
}
__device__ __forceinline__ float bf2f(unsigned short u) {
    return __uint_as_float(((unsigned int)u) << 16);
}
__device__ __forceinline__ f32x4 mfma16(bf16x8 a, bf16x8 b, f32x4 c) {
    return __builtin_amdgcn_mfma_f32_16x16x32_bf16(a, b, c, 0, 0, 0);
}

// ---------------------------------------------------------------------------
// k_prep: weight repack (blocks 0..767) + program decode/state init (768..1023)
// ---------------------------------------------------------------------------
struct PrepArgs { const float* src[12]; const int* prog; char* ws; };

__global__ __launch_bounds__(256) void k_prep(PrepArgs a)
{
    char* ws = a.ws;
    const int bx = blockIdx.x;
    if (bx < 768) {
        const int y = bx >> 6;
        const float* __restrict__ src = a.src[y];
        int gid = (bx & 63) * 256 + threadIdx.x;
        int gsz = 64 * 256;
        if (y == 11) {
            unsigned short* dst = (unsigned short*)(ws + B_WCLS);
            for (int i = gid; i < 131072; i += gsz) dst[i] = f2bf(src[i]);
        } else {
            const int IC = (y == 0) ? 1024 : 128;
            const int lg = (y == 0) ? 10 : 7;
            unsigned short* dst = (unsigned short*)(ws + ((y == 0) ? B_WSTEM1
                                        : (y == 1) ? B_WSTEM2
                                        : B_WMOD + (size_t)(y - 2) * 294912));
            const int total = 9 << (lg + 7);
            for (int i = gid; i < total; i += gsz) {
                int ic = i & (IC - 1);
                int oc = (i >> lg) & 127;
                int t  = i >> (lg + 7);
                dst[i] = f2bf(src[((size_t)oc * IC + ic) * 9 + t]);
            }
        }
        return;
    }
    // decode + state init
    int gid = (bx - 768) * 256 + threadIdx.x;
    int gsz = 256 * 256;
    float* attn  = (float*)(ws + B_ATTN);
    float* saved = (float*)(ws + B_SAVED);
    float* p1    = (float*)(ws + B_P1X1);
    for (int i = gid; i < 64 * 196; i += gsz) { attn[i] = 1.0f; saved[i] = 1.0f; }
    for (int i = gid; i < 8 * 64 * 196; i += gsz) p1[i] = 0.0f;
    unsigned int* fz = (unsigned int*)(ws + B_FEAT);
    for (int i = gid; i < 64 * 25088 / 2; i += gsz) fz[i] = 0u;
    if (gid < 64) {
        int n = gid;
        const int* prog = a.prog;
        int ent[NROUNDS];
        for (int r = 0; r < NROUNDS; ++r) ent[r] = 0;
        int rc = 0, nslot = 0;
        int pscene = 0, pinter = 0, pmat = 0, pmw = 0;
#define PREBITS ((pscene<<17)|(pinter<<18)|(pmat<<19)|(pmw<<22))
#define CLRPRE  (pscene = pinter = pmat = pmw = 0)
#define EMIT(v) do { if (rc < NROUNDS) ent[rc++] = (v); } while (0)
        for (int j = 7; j >= 0; --j) {
            int t = prog[n * 8 + j];
            switch (t) {
                case 3: pscene = 1; break;               // SCENE
                case 4: pinter = 1; break;               // INTERSECT
                case 5: {                                 // FILT
                    int e1 = 3 | (0<<4) | (1<<8) | (1<<12) | (2<<13) | (0<<15) | PREBITS;
                    CLRPRE; EMIT(e1);
                    EMIT(3 | (1<<4) | (1<<8) | (0<<12) | (0<<13) | (1<<15)
                           | (1<<23) | (0<<24) | (nslot<<25));
                    pmat = nslot + 1; pmw = 0; nslot++;
                    break;
                }
                case 6: {                                 // RELATE
                    int e1 = 3 | (2<<4) | (1<<8) | (1<<12) | (2<<13) | (0<<15) | PREBITS;
                    CLRPRE; EMIT(e1);
                    EMIT(3 | (3<<4) | (2<<8) | (0<<12) | (0<<13) | (1<<15));
                    EMIT(3 | (4<<4) | (4<<8) | (0<<12) | (1<<13) | (0<<15));
                    EMIT(3 | (5<<4) | (8<<8) | (0<<12) | (0<<13) | (1<<15));
                    EMIT(3 | (6<<4) | (1<<8) | (0<<12) | (1<<13) | (0<<15)
                           | (1<<23) | (1<<24) | (nslot<<25));
                    pmat = nslot + 1; pmw = 1; nslot++;
                    break;
                }
                case 7: {                                 // QUERY
                    int e1 = 3 | (7<<4) | (1<<8) | (1<<12) | (2<<13) | (0<<15) | PREBITS;
                    CLRPRE; EMIT(e1);
                    EMIT(3 | (8<<4) | (1<<8) | (0<<12) | (0<<13) | (2<<15));
                    break;
                }
                default: break;
            }
        }
#undef EMIT
#undef PREBITS
#undef CLRPRE
        int* sched = (int*)(ws + B_SCHED);
        for (int r = 0; r < NROUNDS; ++r) sched[n * NROUNDS + r] = ent[r];
    }
}

// ---------------------------------------------------------------------------
// stem1 partial conv: block = (n, ks 0..7), 512 threads, ONE 128-ic slab.
// ---------------------------------------------------------------------------
__global__ __launch_bounds__(512) void k_stem1p(const float* __restrict__ feats,
                                                const unsigned short* __restrict__ wrep,
                                                char* ws)
{
    __shared__ unsigned short s_img[197 * 136];
    const int bx = blockIdx.x;
    const int n = bx >> 3, ks = bx & 7;
    const int tid = threadIdx.x, lane = tid & 63;
    const int w = tid >> 6, wm = w & 1, wn = w >> 1;
    const int l15 = lane & 15, lq = lane >> 4;

    if (tid < 68) ((unsigned int*)s_img)[196 * 68 + tid] = 0u;   // zero row

    int pglob[4], pbyt[4], pyv[4], pxv[4];
#pragma unroll
    for (int j = 0; j < 4; ++j) {
        int p  = (wn + 4 * j) * 16 + l15;
        pglob[j] = p;
        int py = p / 14;
        pyv[j] = (p < 196) ? py : 10000;
        pxv[j] = p - py * 14;
        pbyt[j] = p * 272 + lq * 16;
    }
    const int zaddr = 196 * 272 + lq * 16;
    const int nJ = (wn == 0) ? 4 : 3;

    f32x4 acc[4][4];
#pragma unroll
    for (int m = 0; m < 4; ++m)
#pragma unroll
        for (int j = 0; j < 4; ++j) acc[m][j] = (f32x4){0.f, 0.f, 0.f, 0.f};

    const int icg = tid & 31;
    const int qq0 = tid >> 5;
    const int icb = ks * 128;

    const float* sf = feats + ((size_t)n * 1024 + icb) * 196;
    for (int qq = qq0; qq < 49; qq += 16) {
        const float* p0 = sf + icg * 4 * 196 + qq * 4;
        float4 r0 = *(const float4*)(p0);
        float4 r1 = *(const float4*)(p0 + 196);
        float4 r2 = *(const float4*)(p0 + 392);
        float4 r3 = *(const float4*)(p0 + 588);
#pragma unroll
        for (int e = 0; e < 4; ++e) {
            uint2 v;
            v.x = (unsigned int)f2bf(((const float*)&r0)[e]) |
                  ((unsigned int)f2bf(((const float*)&r1)[e]) << 16);
            v.y = (unsigned int)f2bf(((const float*)&r2)[e]) |
                  ((unsigned int)f2bf(((const float*)&r3)[e]) << 16);
            *(uint2*)(s_img + (qq * 4 + e) * 136 + icg * 4) = v;
        }
    }
    __syncthreads();

#pragma unroll
    for (int t = 0; t < 9; ++t) {
        const int dy = t / 3 - 1, dx = t % 3 - 1;
        int baddr[4];
#pragma unroll
        for (int j = 0; j < 4; ++j) {
            int yy = pyv[j] + dy, xx = pxv[j] + dx;
            bool ok = ((unsigned)yy < 14u) && ((unsigned)xx < 14u);
            baddr[j] = ok ? (pbyt[j] + (dy * 14 + dx) * 272) : zaddr;
        }
#pragma unroll
        for (int kc = 0; kc < 4; ++kc) {
            const unsigned short* wt = wrep +
                ((size_t)(t * 128 + wm * 64 + l15) * 1024 + icb + kc * 32 + lq * 8);
            bf16x8 am[4];
#pragma unroll
            for (int m = 0; m < 4; ++m)
                am[m] = *(const bf16x8*)(wt + (size_t)m * 16 * 1024);
#pragma unroll
            for (int j = 0; j < 4; ++j) {
                if (j < nJ) {
                    bf16x8 b = *(const bf16x8*)((const char*)s_img + baddr[j] + kc * 64);
#pragma unroll
                    for (int m = 0; m < 4; ++m)
                        acc[m][j] = mfma16(am[m], b, acc[m][j]);
                }
            }
        }
    }

    unsigned short* part = (unsigned short*)(ws + B_S1P);
#pragma unroll
    for (int m = 0; m < 4; ++m) {
        const int oc = wm * 64 + m * 16 + lq * 4;
#pragma unroll
        for (int j = 0; j < 4; ++j) {
            if (j < nJ) {
                int p = pglob[j];
                if (p < 196) {
                    unsigned int lo = (unsigned int)f2bf(acc[m][j][0]) |
                                      ((unsigned int)f2bf(acc[m][j][1]) << 16);
                    unsigned int hi = (unsigned int)f2bf(acc[m][j][2]) |
                                      ((unsigned int)f2bf(acc[m][j][3]) << 16);
                    uint2 pk; pk.x = lo; pk.y = hi;
                    *(uint2*)(part + (((size_t)ks * 64 + n) * 196 + p) * 128 + oc) = pk;
                }
            }
        }
    }
}

// ---------------------------------------------------------------------------
// 512-thread conv core for k_interp: block covers (sample n, oct 32-oc tile),
// all 196 px. 8 waves: wm = w&1 (16-oc), wn = w>>1 (px interleave nt=wn+4j).
// ---------------------------------------------------------------------------
__device__ void conv512(const unsigned short* __restrict__ src,
                        const float* __restrict__ s_gate,
                        const unsigned short* __restrict__ wrep,   // full set base
                        const float* __restrict__ bias,
                        unsigned short* __restrict__ dst,
                        int dil, int oct,
                        unsigned short* s_img,
                        int post, const float* __restrict__ pwv,
                        float* __restrict__ pdst)
{
    const int tid = threadIdx.x, lane = tid & 63;
    const int w = tid >> 6, wm = w & 1, wn = w >> 1;
    const int l15 = lane & 15, lq = lane >> 4;

    if (tid < 68) ((unsigned int*)s_img)[196 * 68 + tid] = 0u;

    if (s_gate) {
        for (int i = tid; i < 196 * 16; i += 512) {
            int p = i >> 4, c8 = (i & 15) * 8;
            short8 v = *(const short8*)(src + p * 128 + c8);
            float g = s_gate[p];
            short8 ov;
#pragma unroll
            for (int e = 0; e < 8; ++e)
                ov[e] = (short)f2bf(bf2f((unsigned short)v[e]) * g);
            *(short8*)(s_img + p * 136 + c8) = ov;
        }
    } else {
        for (int i = tid; i < 196 * 16; i += 512) {
            int p = i >> 4, c8 = (i & 15) * 8;
            *(short8*)(s_img + p * 136 + c8) = *(const short8*)(src + p * 128 + c8);
        }
    }
    __syncthreads();

    int pglob[4], pbyt[4], pyv[4], pxv[4];
#pragma unroll
    for (int j = 0; j < 4; ++j) {
        int p  = (wn + 4 * j) * 16 + l15;
        pglob[j] = p;
        int py = p / 14;
        pyv[j] = (p < 196) ? py : 10000;
        pxv[j] = p - py * 14;
        pbyt[j] = p * 272 + lq * 16;
    }
    const int zaddr = 196 * 272 + lq * 16;
    const int nJ = (wn == 0) ? 4 : 3;

    f32x4 acc[4];
#pragma unroll
    for (int j = 0; j < 4; ++j) acc[j] = (f32x4){0.f, 0.f, 0.f, 0.f};

    const unsigned short* wlane = wrep + (size_t)(oct * 32 + wm * 16 + l15) * 128 + lq * 8;
#pragma unroll
    for (int t = 0; t < 9; ++t) {
        const int dy = (t / 3 - 1) * dil, dx = (t % 3 - 1) * dil;
        int baddr[4];
#pragma unroll
        for (int j = 0; j < 4; ++j) {
            int yy = pyv[j] + dy, xx = pxv[j] + dx;
            bool ok = ((unsigned)yy < 14u) && ((unsigned)xx < 14u);
            baddr[j] = ok ? (pbyt[j] + (dy * 14 + dx) * 272) : zaddr;
        }
        const unsigned short* wt = wlane + (size_t)(t * 128) * 128;
#pragma unroll
        for (int kc = 0; kc < 4; ++kc) {
            bf16x8 a0 = *(const bf16x8*)(wt + kc * 32);
#pragma unroll
            for (int j = 0; j < 4; ++j) {
                if (j < nJ) {
                    bf16x8 b = *(const bf16x8*)((const char*)s_img + baddr[j] + kc * 64);
                    acc[j] = mfma16(a0, b, acc[j]);
                }
            }
        }
    }

    const int oc = oct * 32 + wm * 16 + lq * 4;
    const float4 b4 = *(const float4*)(bias + oc);
    float4 wv4;
    if (post) wv4 = *(const float4*)(pwv + oc);
#pragma unroll
    for (int j = 0; j < 4; ++j) {
        if (j < nJ) {
            int p = pglob[j];
            if (p < 196) {
                float v0 = fmaxf(acc[j][0] + b4.x, 0.f);
                float v1 = fmaxf(acc[j][1] + b4.y, 0.f);
                float v2 = fmaxf(acc[j][2] + b4.z, 0.f);
                float v3 = fmaxf(acc[j][3] + b4.w, 0.f);
                uint2 pk;
                pk.x = (unsigned int)f2bf(v0) | ((unsigned int)f2bf(v1) << 16);
                pk.y = (unsigned int)f2bf(v2) | ((unsigned int)f2bf(v3) << 16);
                *(uint2*)(dst + p * 128 + oc) = pk;
                if (post) {
                    float s = v0 * wv4.x + v1 * wv4.y + v2 * wv4.z + v3 * wv4.w;
                    atomicAdd(pdst + p, s);
                }
            }
        }
    }
}

// ---------------------------------------------------------------------------
// k_interp (cooperative): stem1-reduce -> stem2 -> 11 conv rounds.
// grid = 256 blocks (n, oct), 512 threads.
// ---------------------------------------------------------------------------
struct IArgs {
    char* ws;
    const float* stem1b;
    const float* stem2b;
    const float* mbias[9];
    const float* w1x1[2];
    const float* b1x1[2];
};

__global__ __launch_bounds__(512) void k_interp(IArgs a)
{
    __shared__ unsigned short s_img[197 * 136];
    __shared__ float s_gate[196];
    cg::grid_group grid = cg::this_grid();
    char* ws = a.ws;
    const int bx = blockIdx.x;
    const int n = bx >> 2, oct = bx & 3;
    const int tid = threadIdx.x;

    // phase 0: stem1 reduce (grid-stride over 64*196*16 short8 groups)
    {
        const unsigned short* part = (const unsigned short*)(ws + B_S1P);
        unsigned short* xa = (unsigned short*)(ws + B_XA);
        for (int i = bx * 512 + tid; i < 64 * 196 * 16; i += 256 * 512) {
            int oc8 = (i & 15) * 8;
            int np  = i >> 4;
            float s[8] = {};
#pragma unroll
            for (int ks = 0; ks < 8; ++ks) {
                short8 v = *(const short8*)(part + (((size_t)ks * 64) * 196 + np) * 128 + oc8);
#pragma unroll
                for (int e = 0; e < 8; ++e) s[e] += bf2f((unsigned short)v[e]);
            }
            short8 o;
#pragma unroll
            for (int e = 0; e < 8; ++e)
                o[e] = (short)f2bf(fmaxf(s[e] + a.stem1b[oc8 + e], 0.f));
            *(short8*)(xa + (size_t)np * 128 + oc8) = o;
        }
    }
    grid.sync();

    // stem2: XA -> STEM
    conv512((const unsigned short*)(ws + B_XA) + (size_t)n * 25088, nullptr,
            (const unsigned short*)(ws + B_WSTEM2), a.stem2b,
            (unsigned short*)(ws + B_STEM) + (size_t)n * 25088,
            1, oct, s_img, 0, nullptr, nullptr);
    grid.sync();

    const int* sched = (const int*)(ws + B_SCHED);
    float* attn  = (float*)(ws + B_ATTN)  + n * 196;
    float* saved = (float*)(ws + B_SAVED) + n * 196;
    float* p1    = (float*)(ws + B_P1X1);

    for (int r = 0; r < NROUNDS; ++r) {
        const int e = sched[n * NROUNDS + r];
        if (e & 15) {
            const int wset = (e >> 4) & 15, dil = (e >> 8) & 15, gatef = (e >> 12) & 1;
            const int srcid = (e >> 13) & 3, dstid = (e >> 15) & 3;
            const int fscene = (e >> 17) & 1, finter = (e >> 18) & 1;
            const int mslot = (e >> 19) & 7, mw = (e >> 22) & 1;
            const int post = (e >> 23) & 1, pw = (e >> 24) & 1, pslot = (e >> 25) & 7;

            if (gatef) {
                if (tid < 196) {
                    float cur = attn[tid];
                    if (mslot) {
                        float pv = p1[(size_t)(mslot - 1) * 12544 + n * 196 + tid];
                        cur = 1.0f / (1.0f + __expf(-(pv + a.b1x1[mw][0])));
                    }
                    if (fscene) { saved[tid] = cur; cur = 1.0f; }
                    if (finter) { cur = fminf(cur, saved[tid]); }
                    if (mslot | fscene | finter) attn[tid] = cur;
                    s_gate[tid] = cur;
                }
                __syncthreads();
            }

            const unsigned short* src = (const unsigned short*)(ws +
                    (srcid == 2 ? B_STEM : srcid == 1 ? B_XB : B_XA)) + (size_t)n * 25088;
            unsigned short* dst = (unsigned short*)(ws +
                    (dstid == 2 ? B_FEAT : dstid == 1 ? B_XB : B_XA)) + (size_t)n * 25088;
            const unsigned short* wrep = (const unsigned short*)(ws + B_WMOD)
                                         + (size_t)wset * 9 * 128 * 128;
            conv512(src, gatef ? s_gate : nullptr, wrep, a.mbias[wset], dst,
                    dil, oct, s_img,
                    post, post ? a.w1x1[pw] : nullptr,
                    post ? (p1 + (size_t)pslot * 12544 + n * 196) : nullptr);
        }
        grid.sync();
    }
}

// ---------------------------------------------------------------------------
// cls 1x1 conv (128->1024, MFMA) + bias + relu + 2x2 maxpool -> actB bf16
// permuted fc1-B layout: k -> kb=k>>6, lq2=(k>>4)&3, hi=(k>>3)&1, e=k&7
// ---------------------------------------------------------------------------
__global__ __launch_bounds__(256) void k_cls_pool(const unsigned short* __restrict__ featall,
                                                  const unsigned short* __restrict__ clsw,
                                                  const float* __restrict__ clsb,
                                                  unsigned short* __restrict__ actB)
{
    __shared__ char smem[197 * 272 + 64 * 200 * 4];
    unsigned short* s_img = (unsigned short*)smem;
    float* s_pool = (float*)(smem + 197 * 272);
    const int n = blockIdx.x >> 4, pt = blockIdx.x & 15;
    const int tid = threadIdx.x, lane = tid & 63, w = tid >> 6;
    const int l15 = lane & 15, lq = lane >> 4;
    const unsigned short* feat = featall + (size_t)n * 25088;

    if (tid < 68) ((unsigned int*)s_img)[196 * 68 + tid] = 0u;
    for (int i = tid; i < 196 * 16; i += 256) {
        int p = i >> 4, c8 = (i & 15) * 8;
        *(short8*)(s_img + p * 136 + c8) = *(const short8*)(feat + p * 128 + c8);
    }
    f32x4 acc[14];
#pragma unroll
    for (int j = 0; j < 14; ++j) acc[j] = (f32x4){0.f, 0.f, 0.f, 0.f};
    __syncthreads();

    const unsigned short* wl = clsw + (size_t)(pt * 64 + w * 16 + l15) * 128 + lq * 8;
#pragma unroll
    for (int kc = 0; kc < 4; ++kc) {
        bf16x8 a0 = *(const bf16x8*)(wl + kc * 32);
#pragma unroll
        for (int j = 0; j < 14; ++j) {
            int p = j * 16 + l15;
            int ba = (p < 196) ? (p * 272 + lq * 16 + kc * 64) : (196 * 272 + lq * 16);
            bf16x8 b = *(const bf16x8*)((const char*)s_img + ba);
            acc[j] = mfma16(a0, b, acc[j]);
        }
    }
    const int oc = pt * 64 + w * 16 + lq * 4;
    const float4 b4 = *(const float4*)(clsb + oc);
    const int pl = w * 16 + lq * 4;
#pragma unroll
    for (int j = 0; j < 14; ++j) {
        int p = j * 16 + l15;
        if (p < 196) {
            s_pool[(pl + 0) * 200 + p] = fmaxf(acc[j][0] + b4.x, 0.f);
            s_pool[(pl + 1) * 200 + p] = fmaxf(acc[j][1] + b4.y, 0.f);
            s_pool[(pl + 2) * 200 + p] = fmaxf(acc[j][2] + b4.z, 0.f);
            s_pool[(pl + 3) * 200 + p] = fmaxf(acc[j][3] + b4.w, 0.f);
        }
    }
    __syncthreads();
    for (int i = tid; i < 64 * 49; i += 256) {
        int plx = i / 49, q = i - plx * 49;
        int py = q / 7, qx = q - py * 7;
        const float* rp = s_pool + plx * 200 + py * 28 + qx * 2;
        float m = fmaxf(fmaxf(rp[0], rp[1]), fmaxf(rp[14], rp[15]));
        int k = (pt * 64 + plx) * 49 + q;
        int kb = k >> 6, lq2 = (k >> 4) & 3, hi = (k >> 3) & 1, e = k & 7;
        actB[((((size_t)kb * 4 + lq2) * 2 + hi) * 64 + n) * 8 + e] = f2bf(m);
    }
}

// ---------------------------------------------------------------------------
// fc1 partial GEMM with LDS-staged W tile. NKS=98, KC=512 (2 stage steps).
// ---------------------------------------------------------------------------
__global__ __launch_bounds__(256) void k_fc1p(const unsigned short* __restrict__ actB,
                                              const float* __restrict__ w,
                                              float* __restrict__ part)
{
    __shared__ unsigned short s_w[64 * 264];
    const int jt = blockIdx.x & 15, ks = blockIdx.x >> 4;
    const int tid = threadIdx.x, lane = tid & 63, wv = tid >> 6;
    const int l15 = lane & 15, lq = lane >> 4;
    const int k0 = ks * 512;
    const int r4 = tid & 3, l4 = (tid >> 2) & 15, rw = tid >> 6;

    f32x4 acc[4];
#pragma unroll
    for (int t = 0; t < 4; ++t) acc[t] = (f32x4){0.f, 0.f, 0.f, 0.f};

    float4 pf[4][4];

#define FC1_LOAD(ss_) do {                                                        \
    _Pragma("unroll")                                                             \
    for (int pass = 0; pass < 4; ++pass) {                                        \
        const int row_ = pass * 16 + rw * 4 + r4;                                 \
        const float* wp_ = w + (size_t)(jt * 64 + row_) * 50176 + k0              \
                             + (ss_) * 256 + l4 * 16;                             \
        pf[pass][0] = *(const float4*)(wp_);                                      \
        pf[pass][1] = *(const float4*)(wp_ + 4);                                  \
        pf[pass][2] = *(const float4*)(wp_ + 8);                                  \
        pf[pass][3] = *(const float4*)(wp_ + 12);                                 \
    } } while (0)

    FC1_LOAD(0);

    for (int ss = 0; ss < 2; ++ss) {
        __syncthreads();
#pragma unroll
        for (int pass = 0; pass < 4; ++pass) {
            const int row = pass * 16 + rw * 4 + r4;
            bf16x8 c0, c1;
            c0[0] = (__bf16)pf[pass][0].x; c0[1] = (__bf16)pf[pass][0].y;
            c0[2] = (__bf16)pf[pass][0].z; c0[3] = (__bf16)pf[pass][0].w;
            c0[4] = (__bf16)pf[pass][1].x; c0[5] = (__bf16)pf[pass][1].y;
            c0[6] = (__bf16)pf[pass][1].z; c0[7] = (__bf16)pf[pass][1].w;
            c1[0] = (__bf16)pf[pass][2].x; c1[1] = (__bf16)pf[pass][2].y;
            c1[2] = (__bf16)pf[pass][2].z; c1[3] = (__bf16)pf[pass][2].w;
            c1[4] = (__bf16)pf[pass][3].x; c1[5] = (__bf16)pf[pass][3].y;
            c1[6] = (__bf16)pf[pass][3].z; c1[7] = (__bf16)pf[pass][3].w;
            *(bf16x8*)(s_w + row * 264 + l4 * 16)     = c0;
            *(bf16x8*)(s_w + row * 264 + l4 * 16 + 8) = c1;
        }
        __syncthreads();
        if (ss < 1) FC1_LOAD(1);

        const unsigned short* arow = s_w + (wv * 16 + l15) * 264;
#pragma unroll
        for (int kk = 0; kk < 8; ++kk) {
            bf16x8 a = *(const bf16x8*)(arow + kk * 32 + lq * 8);
            const int kglob = k0 + ss * 256 + kk * 32 + lq * 8;
            const int kb = kglob >> 6, lq2 = (kglob >> 4) & 3, hi = (kglob >> 3) & 1;
            const unsigned short* bp = actB +
                ((((size_t)kb * 4 + lq2) * 2 + hi) * 64 + l15) * 8;
#pragma unroll
            for (int t = 0; t < 4; ++t) {
                bf16x8 b = *(const bf16x8*)(bp + t * 128);
                acc[t] = mfma16(a, b, acc[t]);
            }
        }
    }
#undef FC1_LOAD

    float* pbase = part + ((size_t)ks * 1024 + jt * 64 + wv * 16 + lq * 4) * 64 + l15;
#pragma unroll
    for (int t = 0; t < 4; ++t)
#pragma unroll
        for (int r = 0; r < 4; ++r)
            pbase[(size_t)r * 64 + t * 16] = acc[t][r];
}

// ---------------------------------------------------------------------------
// k_fc1tail (cooperative, 256 blocks x 256): fc1 reduce+bias+relu, sync, fc2.
// ---------------------------------------------------------------------------
__global__ __launch_bounds__(256) void k_fc1tail(const float* __restrict__ part,
                                                 const float* __restrict__ b1,
                                                 const float* __restrict__ w2,
                                                 const float* __restrict__ b2,
                                                 float* __restrict__ fc1T,
                                                 float* __restrict__ out)
{
    cg::grid_group grid = cg::this_grid();
    __shared__ float red[256];
    {
        int i = blockIdx.x * 256 + threadIdx.x;   // 65536 threads, 1 elem each
        float s = 0.0f;
        for (int ks = 0; ks < NKS; ++ks) s += part[(size_t)ks * 65536 + i];
        fc1T[i] = fmaxf(s + b1[i >> 6], 0.0f);
    }
    grid.sync();
    if (blockIdx.x < 28) {
        const int a_ = blockIdx.x;
        const int tid = threadIdx.x, lane = tid & 63, q = tid >> 6;
        float acc = 0.0f;
        const float* wr = w2 + (size_t)a_ * 1024;
        for (int k = q * 256; k < q * 256 + 256; ++k)
            acc = fmaf(fc1T[k * 64 + lane], wr[k], acc);
        red[tid] = acc;
        __syncthreads();
        if (q == 0) {
            float s = red[tid] + red[tid + 64] + red[tid + 128] + red[tid + 192] + b2[a_];
            out[lane * 28 + a_] = s;
        }
    }
}

extern "C" void kernel_launch(void* const* d_in, const int* in_sizes, int n_in,
                              void* d_out, int out_size, void* d_ws, size_t ws_size,
                              hipStream_t stream)
{
    const float* feats = (const float*)d_in[0];
    const int*   prog  = (const int*)d_in[1];
    char* ws  = (char*)d_ws;
    float* out = (float*)d_out;

    PrepArgs pa;
    pa.src[0]  = (const float*)d_in[2];   // stem_w1
    pa.src[1]  = (const float*)d_in[4];   // stem_w2
    pa.src[2]  = (const float*)d_in[6];   // att_w1
    pa.src[3]  = (const float*)d_in[8];   // att_w2
    pa.src[4]  = (const float*)d_in[12];  // rel_w1
    pa.src[5]  = (const float*)d_in[14];  // rel_w2
    pa.src[6]  = (const float*)d_in[16];  // rel_w3
    pa.src[7]  = (const float*)d_in[18];  // rel_w4
    pa.src[8]  = (const float*)d_in[20];  // rel_w5
    pa.src[9]  = (const float*)d_in[24];  // qry_w1
    pa.src[10] = (const float*)d_in[26];  // qry_w2
    pa.src[11] = (const float*)d_in[28];  // cls_w
    pa.prog = prog;
    pa.ws = ws;
    k_prep<<<1024, 256, 0, stream>>>(pa);

    k_stem1p<<<512, 512, 0, stream>>>(feats, (const unsigned short*)(ws + B_WSTEM1), ws);

    IArgs ia;
    ia.ws = ws;
    ia.stem1b = (const float*)d_in[3];
    ia.stem2b = (const float*)d_in[5];
    ia.mbias[0] = (const float*)d_in[7];   // att_b1
    ia.mbias[1] = (const float*)d_in[9];   // att_b2
    ia.mbias[2] = (const float*)d_in[13];  // rel_b1
    ia.mbias[3] = (const float*)d_in[15];  // rel_b2
    ia.mbias[4] = (const float*)d_in[17];  // rel_b3
    ia.mbias[5] = (const float*)d_in[19];  // rel_b4
    ia.mbias[6] = (const float*)d_in[21];  // rel_b5
    ia.mbias[7] = (const float*)d_in[25];  // qry_b1
    ia.mbias[8] = (const float*)d_in[27];  // qry_b2
    ia.w1x1[0]  = (const float*)d_in[10];  // att_w3
    ia.w1x1[1]  = (const float*)d_in[22];  // rel_w6
    ia.b1x1[0]  = (const float*)d_in[11];  // att_b3
    ia.b1x1[1]  = (const float*)d_in[23];  // rel_b6
    void* kp1[] = { (void*)&ia };
    hipLaunchCooperativeKernel((const void*)k_interp, dim3(256), dim3(512),
                               kp1, 0, stream);

    k_cls_pool<<<1024, 256, 0, stream>>>((const unsigned short*)(ws + B_FEAT),
                                         (const unsigned short*)(ws + B_WCLS),
                                         (const float*)d_in[29],
                                         (unsigned short*)(ws + B_ACTB));
    k_fc1p<<<1568, 256, 0, stream>>>((const unsigned short*)(ws + B_ACTB),
                                     (const float*)d_in[30], (float*)(ws + B_FC1P));

    const float* partp = (const float*)(ws + B_FC1P);
    const float* b1p   = (const float*)d_in[31];
    const float* w2p   = (const float*)d_in[32];
    const float* b2p   = (const float*)d_in[33];
    float* fc1Tp = (float*)(ws + B_FC1T);
    float* outp  = out;
    void* kp2[] = { (void*)&partp, (void*)&b1p, (void*)&w2p, (void*)&b2p,
                    (void*)&fc1Tp, (void*)&outp };
    hipLaunchCooperativeKernel((const void*)k_fc1tail, dim3(256), dim3(256),
                               kp2, 0, stream);
}

// Round 10
// 511.396 us; speedup vs baseline: 1.5361x; 1.5361x over previous
//
#include <hip/hip_runtime.h>
#include <math.h>

// ---------------------------------------------------------------------------
// TbDNet forward, round 10: round-8 structure (best: serial round launches),
// with fc1p staging rebuilt for perfect per-wave 1KB-contiguous loads and
// NROUNDS=11.
// ---------------------------------------------------------------------------

typedef __attribute__((ext_vector_type(8)))  short   short8;
typedef __attribute__((ext_vector_type(8)))  __bf16  bf16x8;
typedef __attribute__((ext_vector_type(4)))  float   f32x4;

#define NROUNDS 11
#define NKS 98          // fc1 K-splits (KC = 512)

// byte offsets in ws
#define B_WSTEM1 0UL                 // bf16 [9][128][1024]
#define B_WSTEM2 2359296UL           // bf16 [9][128][128]
#define B_WMOD   2654208UL           // 9 x bf16 [9][128][128]
#define B_WCLS   5308416UL           // bf16 [1024][128]
#define B_STEM   5570560UL           // bf16 [64][196][128]
#define B_XA     8781824UL
#define B_XB     11993088UL
#define B_FEAT   15204352UL
#define B_ATTN   18415616UL          // f32 [64][196]
#define B_SAVED  18465792UL
#define B_SCHED  18515968UL          // int [64][NROUNDS]
#define B_ACTB   18520064UL          // bf16 permuted fc1-B
#define B_FC1T   24942592UL          // f32 [1024][64]
#define B_P1X1   25204736UL          // f32 [8 slots][64][196]
// high overlays (ws ~800 MB):
#define B_S1P    67108864UL          // stem1 partials bf16 [8][64][196][128]
#define B_FC1P   100663296UL         // fc1 partials f32 [98][1024][64]

__device__ __forceinline__ unsigned short f2bf(float f) {
    unsigned int b = __float_as_uint(f);
    b += 0x7fffu + ((b >> 16) & 1u);          // RNE
    return (unsigned short)(b >> 16);
}
__device__ __forceinline__ float bf2f(unsigned short u) {
    return __uint_as_float(((unsigned int)u) << 16);
}
__device__ __forceinline__ f32x4 mfma16(bf16x8 a, bf16x8 b, f32x4 c) {
    return __builtin_amdgcn_mfma_f32_16x16x32_bf16(a, b, c, 0, 0, 0);
}

// ---------------------------------------------------------------------------
// Weight repack.
// ---------------------------------------------------------------------------
struct RepackArgs { const float* src[12]; };

__global__ __launch_bounds__(256) void k_repack(RepackArgs a, char* ws)
{
    const int y = blockIdx.y;
    const float* __restrict__ src = a.src[y];
    int gid = blockIdx.x * 256 + threadIdx.x;
    int gsz = gridDim.x * 256;
    if (y == 11) {
        unsigned short* dst = (unsigned short*)(ws + B_WCLS);
        for (int i = gid; i < 131072; i += gsz) dst[i] = f2bf(src[i]);
    } else {
        const int IC = (y == 0) ? 1024 : 128;
        const int lg = (y == 0) ? 10 : 7;
        unsigned short* dst = (unsigned short*)(ws + ((y == 0) ? B_WSTEM1
                                    : (y == 1) ? B_WSTEM2
                                    : B_WMOD + (size_t)(y - 2) * 294912));
        const int total = 9 << (lg + 7);
        for (int i = gid; i < total; i += gsz) {
            int ic = i & (IC - 1);
            int oc = (i >> lg) & 127;
            int t  = i >> (lg + 7);
            dst[i] = f2bf(src[((size_t)oc * IC + ic) * 9 + t]);
        }
    }
}

// ---------------------------------------------------------------------------
// Program decode + state init. Conv-only entries (round-8 encoding).
// ---------------------------------------------------------------------------
__global__ __launch_bounds__(256) void k_decode_init(const int* __restrict__ prog, char* ws)
{
    int gid = blockIdx.x * 256 + threadIdx.x;
    int gsz = gridDim.x * 256;
    float* attn  = (float*)(ws + B_ATTN);
    float* saved = (float*)(ws + B_SAVED);
    float* p1    = (float*)(ws + B_P1X1);
    for (int i = gid; i < 64 * 196; i += gsz) { attn[i] = 1.0f; saved[i] = 1.0f; }
    for (int i = gid; i < 8 * 64 * 196; i += gsz) p1[i] = 0.0f;
    unsigned int* fz = (unsigned int*)(ws + B_FEAT);
    for (int i = gid; i < 64 * 25088 / 2; i += gsz) fz[i] = 0u;
    if (gid < 64) {
        int n = gid;
        int ent[NROUNDS];
        for (int r = 0; r < NROUNDS; ++r) ent[r] = 0;
        int rc = 0, nslot = 0;
        int pscene = 0, pinter = 0, pmat = 0, pmw = 0;
#define PREBITS ((pscene<<17)|(pinter<<18)|(pmat<<19)|(pmw<<22))
#define CLRPRE  (pscene = pinter = pmat = pmw = 0)
#define EMIT(v) do { if (rc < NROUNDS) ent[rc++] = (v); } while (0)
        for (int j = 7; j >= 0; --j) {
            int t = prog[n * 8 + j];
            switch (t) {
                case 3: pscene = 1; break;               // SCENE
                case 4: pinter = 1; break;               // INTERSECT
                case 5: {                                 // FILT
                    int e1 = 3 | (0<<4) | (1<<8) | (1<<12) | (2<<13) | (0<<15) | PREBITS;
                    CLRPRE; EMIT(e1);
                    EMIT(3 | (1<<4) | (1<<8) | (0<<12) | (0<<13) | (1<<15)
                           | (1<<23) | (0<<24) | (nslot<<25));
                    pmat = nslot + 1; pmw = 0; nslot++;
                    break;
                }
                case 6: {                                 // RELATE
                    int e1 = 3 | (2<<4) | (1<<8) | (1<<12) | (2<<13) | (0<<15) | PREBITS;
                    CLRPRE; EMIT(e1);
                    EMIT(3 | (3<<4) | (2<<8) | (0<<12) | (0<<13) | (1<<15));
                    EMIT(3 | (4<<4) | (4<<8) | (0<<12) | (1<<13) | (0<<15));
                    EMIT(3 | (5<<4) | (8<<8) | (0<<12) | (0<<13) | (1<<15));
                    EMIT(3 | (6<<4) | (1<<8) | (0<<12) | (1<<13) | (0<<15)
                           | (1<<23) | (1<<24) | (nslot<<25));
                    pmat = nslot + 1; pmw = 1; nslot++;
                    break;
                }
                case 7: {                                 // QUERY
                    int e1 = 3 | (7<<4) | (1<<8) | (1<<12) | (2<<13) | (0<<15) | PREBITS;
                    CLRPRE; EMIT(e1);
                    EMIT(3 | (8<<4) | (1<<8) | (0<<12) | (0<<13) | (2<<15));
                    break;
                }
                default: break;
            }
        }
#undef EMIT
#undef PREBITS
#undef CLRPRE
        int* sched = (int*)(ws + B_SCHED);
        for (int r = 0; r < NROUNDS; ++r) sched[n * NROUNDS + r] = ent[r];
    }
}

// ---------------------------------------------------------------------------
// stem1 partial conv: block = (n, ks 0..7), 512 threads, ONE 128-ic slab.
// ---------------------------------------------------------------------------
__global__ __launch_bounds__(512) void k_stem1p(const float* __restrict__ feats,
                                                const unsigned short* __restrict__ wrep,
                                                char* ws)
{
    __shared__ unsigned short s_img[197 * 136];
    const int bx = blockIdx.x;
    const int n = bx >> 3, ks = bx & 7;
    const int tid = threadIdx.x, lane = tid & 63;
    const int w = tid >> 6, wm = w & 1, wn = w >> 1;
    const int l15 = lane & 15, lq = lane >> 4;

    if (tid < 68) ((unsigned int*)s_img)[196 * 68 + tid] = 0u;   // zero row

    int pglob[4], pbyt[4], pyv[4], pxv[4];
#pragma unroll
    for (int j = 0; j < 4; ++j) {
        int p  = (wn + 4 * j) * 16 + l15;
        pglob[j] = p;
        int py = p / 14;
        pyv[j] = (p < 196) ? py : 10000;
        pxv[j] = p - py * 14;
        pbyt[j] = p * 272 + lq * 16;
    }
    const int zaddr = 196 * 272 + lq * 16;
    const int nJ = (wn == 0) ? 4 : 3;

    f32x4 acc[4][4];
#pragma unroll
    for (int m = 0; m < 4; ++m)
#pragma unroll
        for (int j = 0; j < 4; ++j) acc[m][j] = (f32x4){0.f, 0.f, 0.f, 0.f};

    const int icg = tid & 31;
    const int qq0 = tid >> 5;
    const int icb = ks * 128;

    const float* sf = feats + ((size_t)n * 1024 + icb) * 196;
    for (int qq = qq0; qq < 49; qq += 16) {
        const float* p0 = sf + icg * 4 * 196 + qq * 4;
        float4 r0 = *(const float4*)(p0);
        float4 r1 = *(const float4*)(p0 + 196);
        float4 r2 = *(const float4*)(p0 + 392);
        float4 r3 = *(const float4*)(p0 + 588);
#pragma unroll
        for (int e = 0; e < 4; ++e) {
            uint2 v;
            v.x = (unsigned int)f2bf(((const float*)&r0)[e]) |
                  ((unsigned int)f2bf(((const float*)&r1)[e]) << 16);
            v.y = (unsigned int)f2bf(((const float*)&r2)[e]) |
                  ((unsigned int)f2bf(((const float*)&r3)[e]) << 16);
            *(uint2*)(s_img + (qq * 4 + e) * 136 + icg * 4) = v;
        }
    }
    __syncthreads();

#pragma unroll
    for (int t = 0; t < 9; ++t) {
        const int dy = t / 3 - 1, dx = t % 3 - 1;
        int baddr[4];
#pragma unroll
        for (int j = 0; j < 4; ++j) {
            int yy = pyv[j] + dy, xx = pxv[j] + dx;
            bool ok = ((unsigned)yy < 14u) && ((unsigned)xx < 14u);
            baddr[j] = ok ? (pbyt[j] + (dy * 14 + dx) * 272) : zaddr;
        }
#pragma unroll
        for (int kc = 0; kc < 4; ++kc) {
            const unsigned short* wt = wrep +
                ((size_t)(t * 128 + wm * 64 + l15) * 1024 + icb + kc * 32 + lq * 8);
            bf16x8 am[4];
#pragma unroll
            for (int m = 0; m < 4; ++m)
                am[m] = *(const bf16x8*)(wt + (size_t)m * 16 * 1024);
#pragma unroll
            for (int j = 0; j < 4; ++j) {
                if (j < nJ) {
                    bf16x8 b = *(const bf16x8*)((const char*)s_img + baddr[j] + kc * 64);
#pragma unroll
                    for (int m = 0; m < 4; ++m)
                        acc[m][j] = mfma16(am[m], b, acc[m][j]);
                }
            }
        }
    }

    unsigned short* part = (unsigned short*)(ws + B_S1P);
#pragma unroll
    for (int m = 0; m < 4; ++m) {
        const int oc = wm * 64 + m * 16 + lq * 4;
#pragma unroll
        for (int j = 0; j < 4; ++j) {
            if (j < nJ) {
                int p = pglob[j];
                if (p < 196) {
                    unsigned int lo = (unsigned int)f2bf(acc[m][j][0]) |
                                      ((unsigned int)f2bf(acc[m][j][1]) << 16);
                    unsigned int hi = (unsigned int)f2bf(acc[m][j][2]) |
                                      ((unsigned int)f2bf(acc[m][j][3]) << 16);
                    uint2 pk; pk.x = lo; pk.y = hi;
                    *(uint2*)(part + (((size_t)ks * 64 + n) * 196 + p) * 128 + oc) = pk;
                }
            }
        }
    }
}

// stem1 reduce: sum 8 bf16 partials + bias + relu -> XA bf16 [n][p][128]
__global__ __launch_bounds__(256) void k_stem1r(const char* __restrict__ ws_c,
                                                const float* __restrict__ bias,
                                                unsigned short* __restrict__ xa)
{
    int i = blockIdx.x * 256 + threadIdx.x;
    const unsigned short* part = (const unsigned short*)(ws_c + B_S1P);
    int oc8 = (i & 15) * 8;
    int np  = i >> 4;
    float s[8] = {};
#pragma unroll
    for (int ks = 0; ks < 8; ++ks) {
        short8 v = *(const short8*)(part + (((size_t)ks * 64) * 196 + np) * 128 + oc8);
#pragma unroll
        for (int e = 0; e < 8; ++e) s[e] += bf2f((unsigned short)v[e]);
    }
    short8 o;
#pragma unroll
    for (int e = 0; e < 8; ++e)
        o[e] = (short)f2bf(fmaxf(s[e] + bias[oc8 + e], 0.f));
    *(short8*)(xa + (size_t)np * 128 + oc8) = o;
}

// ---------------------------------------------------------------------------
// MFMA 3x3 dilated conv core, 32-oc tile, optional LDS gate + 1x1 postsum.
// ---------------------------------------------------------------------------
__device__ void conv_core32(const unsigned short* __restrict__ srcB,
                            const float* __restrict__ s_gate,
                            const unsigned short* __restrict__ wrep,
                            const float* __restrict__ bias,
                            unsigned short* __restrict__ dst,
                            int dil, int oct, int pxh,
                            unsigned short* s_img,
                            int post, const float* __restrict__ pwv,
                            float* __restrict__ pdst)
{
    const int tid  = threadIdx.x, lane = tid & 63;
    const int w    = tid >> 6, wm = w & 1, wn = w >> 1;
    const int l15  = lane & 15, lq = lane >> 4;

    if (tid < 68) ((unsigned int*)s_img)[196 * 68 + tid] = 0u;   // zero page row

    int pglob[4], pbyt[4], pyv[4], pxv[4];
#pragma unroll
    for (int j = 0; j < 4; ++j) {
        int nt = wn + 2 * j;
        int p  = (pxh * 7 + nt) * 16 + l15;
        pglob[j] = p;
        int py = p / 14;
        pyv[j] = (p < 196) ? py : 10000;
        pxv[j] = p - py * 14;
        pbyt[j] = p * 272 + lq * 16;
    }
    const int zaddr = 196 * 272 + lq * 16;
    const int nNT = (wn == 0) ? 4 : 3;

    f32x4 acc[4];
#pragma unroll
    for (int j = 0; j < 4; ++j) acc[j] = (f32x4){0.f, 0.f, 0.f, 0.f};

    if (s_gate) {
        for (int i = tid; i < 196 * 16; i += 256) {
            int p = i >> 4, c8 = (i & 15) * 8;
            short8 v = *(const short8*)(srcB + p * 128 + c8);
            float g = s_gate[p];
            short8 ov;
#pragma unroll
            for (int e = 0; e < 8; ++e)
                ov[e] = (short)f2bf(bf2f((unsigned short)v[e]) * g);
            *(short8*)(s_img + p * 136 + c8) = ov;
        }
    } else {
        for (int i = tid; i < 196 * 16; i += 256) {
            int p = i >> 4, c8 = (i & 15) * 8;
            *(short8*)(s_img + p * 136 + c8) = *(const short8*)(srcB + p * 128 + c8);
        }
    }
    __syncthreads();

    const unsigned short* wlane = wrep + (size_t)(oct * 32 + wm * 16 + l15) * 128 + lq * 8;
#pragma unroll
    for (int t = 0; t < 9; ++t) {
        const int dy = (t / 3 - 1) * dil, dx = (t % 3 - 1) * dil;
        int baddr[4];
#pragma unroll
        for (int j = 0; j < 4; ++j) {
            int yy = pyv[j] + dy, xx = pxv[j] + dx;
            bool ok = ((unsigned)yy < 14u) && ((unsigned)xx < 14u);
            baddr[j] = ok ? (pbyt[j] + (dy * 14 + dx) * 272) : zaddr;
        }
        const unsigned short* wt = wlane + (size_t)(t * 128) * 128;
#pragma unroll
        for (int kc = 0; kc < 4; ++kc) {
            bf16x8 a0 = *(const bf16x8*)(wt + kc * 32);
#pragma unroll
            for (int j = 0; j < 4; ++j) {
                if (j < nNT) {
                    bf16x8 b = *(const bf16x8*)((const char*)s_img + baddr[j] + kc * 64);
                    acc[j] = mfma16(a0, b, acc[j]);
                }
            }
        }
    }

    const int oc = oct * 32 + wm * 16 + lq * 4;
    const float4 b4 = *(const float4*)(bias + oc);
    float4 wv4;
    if (post) wv4 = *(const float4*)(pwv + oc);
#pragma unroll
    for (int j = 0; j < 4; ++j) {
        if (j < nNT) {
            int p = pglob[j];
            if (p < 196) {
                float v0 = fmaxf(acc[j][0] + b4.x, 0.f);
                float v1 = fmaxf(acc[j][1] + b4.y, 0.f);
                float v2 = fmaxf(acc[j][2] + b4.z, 0.f);
                float v3 = fmaxf(acc[j][3] + b4.w, 0.f);
                uint2 pk;
                pk.x = (unsigned int)f2bf(v0) | ((unsigned int)f2bf(v1) << 16);
                pk.y = (unsigned int)f2bf(v2) | ((unsigned int)f2bf(v3) << 16);
                *(uint2*)(dst + p * 128 + oc) = pk;
                if (post) {
                    float s = v0 * wv4.x + v1 * wv4.y + v2 * wv4.z + v3 * wv4.w;
                    atomicAdd(pdst + p, s);
                }
            }
        }
    }
}

__global__ __launch_bounds__(256) void k_conv_stem2(const unsigned short* __restrict__ srcBall,
                                                    const unsigned short* __restrict__ wrep,
                                                    const float* __restrict__ bias,
                                                    unsigned short* __restrict__ dstall)
{
    __shared__ unsigned short s_img[197 * 136];
    const int n = blockIdx.x >> 3, oct = (blockIdx.x >> 1) & 3, pxh = blockIdx.x & 1;
    conv_core32(srcBall + (size_t)n * 25088, nullptr, wrep, bias,
                dstall + (size_t)n * 25088, 1, oct, pxh, s_img, 0, nullptr, nullptr);
}

// ---------------------------------------------------------------------------
// Module interpreter round: 512 blocks = (n, oct, pxh). Conv-only entries.
// ---------------------------------------------------------------------------
struct RArgs {
    char* ws;
    const float* mbias[9];
    const float* w1x1[2];
    const float* b1x1[2];
};

__global__ __launch_bounds__(256) void k_round(RArgs a, int r)
{
    __shared__ unsigned short s_img[197 * 136];
    __shared__ float s_gate[196];
    const int bx = blockIdx.x;
    const int n = bx >> 3, oct = (bx >> 1) & 3, pxh = bx & 1;
    char* ws = a.ws;
    const int* sched = (const int*)(ws + B_SCHED);
    const int e = sched[n * NROUNDS + r];
    if ((e & 15) == 0) return;
    const int tid = threadIdx.x;
    const int wset = (e >> 4) & 15, dil = (e >> 8) & 15, gatef = (e >> 12) & 1;
    const int srcid = (e >> 13) & 3, dstid = (e >> 15) & 3;
    const int fscene = (e >> 17) & 1, finter = (e >> 18) & 1;
    const int mslot = (e >> 19) & 7, mw = (e >> 22) & 1;
    const int post = (e >> 23) & 1, pw = (e >> 24) & 1, pslot = (e >> 25) & 7;

    float* attn  = (float*)(ws + B_ATTN)  + n * 196;
    float* saved = (float*)(ws + B_SAVED) + n * 196;
    float* p1    = (float*)(ws + B_P1X1);

    if (gatef) {
        if (tid < 196) {
            float cur = attn[tid];
            if (mslot) {
                float pv = p1[(size_t)(mslot - 1) * 12544 + n * 196 + tid];
                cur = 1.0f / (1.0f + __expf(-(pv + a.b1x1[mw][0])));
            }
            if (fscene) { saved[tid] = cur; cur = 1.0f; }
            if (finter) { cur = fminf(cur, saved[tid]); }
            if (mslot | fscene | finter) attn[tid] = cur;
            s_gate[tid] = cur;
        }
        __syncthreads();
    }

    const unsigned short* src = (const unsigned short*)(ws +
            (srcid == 2 ? B_STEM : srcid == 1 ? B_XB : B_XA)) + (size_t)n * 25088;
    unsigned short* dst = (unsigned short*)(ws +
            (dstid == 2 ? B_FEAT : dstid == 1 ? B_XB : B_XA)) + (size_t)n * 25088;
    const unsigned short* wrep = (const unsigned short*)(ws + B_WMOD) + (size_t)wset * 9 * 128 * 128;

    conv_core32(src, gatef ? s_gate : nullptr, wrep, a.mbias[wset], dst,
                dil, oct, pxh, s_img,
                post, post ? a.w1x1[pw] : nullptr,
                post ? (p1 + (size_t)pslot * 12544 + n * 196) : nullptr);
}

// ---------------------------------------------------------------------------
// cls 1x1 conv (128->1024, MFMA) + bias + relu + 2x2 maxpool -> actB bf16
// permuted fc1-B layout: k -> kb=k>>6, lq2=(k>>4)&3, hi=(k>>3)&1, e=k&7
// ---------------------------------------------------------------------------
__global__ __launch_bounds__(256) void k_cls_pool(const unsigned short* __restrict__ featall,
                                                  const unsigned short* __restrict__ clsw,
                                                  const float* __restrict__ clsb,
                                                  unsigned short* __restrict__ actB)
{
    __shared__ char smem[197 * 272 + 64 * 200 * 4];
    unsigned short* s_img = (unsigned short*)smem;
    float* s_pool = (float*)(smem + 197 * 272);
    const int n = blockIdx.x >> 4, pt = blockIdx.x & 15;
    const int tid = threadIdx.x, lane = tid & 63, w = tid >> 6;
    const int l15 = lane & 15, lq = lane >> 4;
    const unsigned short* feat = featall + (size_t)n * 25088;

    if (tid < 68) ((unsigned int*)s_img)[196 * 68 + tid] = 0u;
    for (int i = tid; i < 196 * 16; i += 256) {
        int p = i >> 4, c8 = (i & 15) * 8;
        *(short8*)(s_img + p * 136 + c8) = *(const short8*)(feat + p * 128 + c8);
    }
    f32x4 acc[14];
#pragma unroll
    for (int j = 0; j < 14; ++j) acc[j] = (f32x4){0.f, 0.f, 0.f, 0.f};
    __syncthreads();

    const unsigned short* wl = clsw + (size_t)(pt * 64 + w * 16 + l15) * 128 + lq * 8;
#pragma unroll
    for (int kc = 0; kc < 4; ++kc) {
        bf16x8 a0 = *(const bf16x8*)(wl + kc * 32);
#pragma unroll
        for (int j = 0; j < 14; ++j) {
            int p = j * 16 + l15;
            int ba = (p < 196) ? (p * 272 + lq * 16 + kc * 64) : (196 * 272 + lq * 16);
            bf16x8 b = *(const bf16x8*)((const char*)s_img + ba);
            acc[j] = mfma16(a0, b, acc[j]);
        }
    }
    const int oc = pt * 64 + w * 16 + lq * 4;
    const float4 b4 = *(const float4*)(clsb + oc);
    const int pl = w * 16 + lq * 4;
#pragma unroll
    for (int j = 0; j < 14; ++j) {
        int p = j * 16 + l15;
        if (p < 196) {
            s_pool[(pl + 0) * 200 + p] = fmaxf(acc[j][0] + b4.x, 0.f);
            s_pool[(pl + 1) * 200 + p] = fmaxf(acc[j][1] + b4.y, 0.f);
            s_pool[(pl + 2) * 200 + p] = fmaxf(acc[j][2] + b4.z, 0.f);
            s_pool[(pl + 3) * 200 + p] = fmaxf(acc[j][3] + b4.w, 0.f);
        }
    }
    __syncthreads();
    for (int i = tid; i < 64 * 49; i += 256) {
        int plx = i / 49, q = i - plx * 49;
        int py = q / 7, qx = q - py * 7;
        const float* rp = s_pool + plx * 200 + py * 28 + qx * 2;
        float m = fmaxf(fmaxf(rp[0], rp[1]), fmaxf(rp[14], rp[15]));
        int k = (pt * 64 + plx) * 49 + q;
        int kb = k >> 6, lq2 = (k >> 4) & 3, hi = (k >> 3) & 1, e = k & 7;
        actB[((((size_t)kb * 4 + lq2) * 2 + hi) * 64 + n) * 8 + e] = f2bf(m);
    }
}

// ---------------------------------------------------------------------------
// fc1 partial GEMM, LDS-staged W tile with per-wave 1KB-contiguous loads.
// Block = (ks 0..97, jt 0..15). KC=512 (2 stage steps of 256 k).
// Stage: pass p (0..15): wave wv loads row p*4+wv, lane covers k-col lane*4
//   -> one dwordx4 per lane = wave reads 1KB contiguous of one W row.
// ---------------------------------------------------------------------------
__global__ __launch_bounds__(256) void k_fc1p(const unsigned short* __restrict__ actB,
                                              const float* __restrict__ w,
                                              float* __restrict__ part)
{
    __shared__ unsigned short s_w[64 * 264];
    const int jt = blockIdx.x & 15, ks = blockIdx.x >> 4;
    const int tid = threadIdx.x, lane = tid & 63, wv = tid >> 6;
    const int l15 = lane & 15, lq = lane >> 4;
    const int k0 = ks * 512;

    f32x4 acc[4];
#pragma unroll
    for (int t = 0; t < 4; ++t) acc[t] = (f32x4){0.f, 0.f, 0.f, 0.f};

    float4 pf[16];

#define FC1_LOAD(ss_) do {                                                        \
    _Pragma("unroll")                                                             \
    for (int pass = 0; pass < 16; ++pass) {                                       \
        const int row_ = pass * 4 + wv;                                           \
        pf[pass] = *(const float4*)(w + (size_t)(jt * 64 + row_) * 50176 + k0     \
                                      + (ss_) * 256 + lane * 4);                  \
    } } while (0)

    FC1_LOAD(0);

    for (int ss = 0; ss < 2; ++ss) {
        __syncthreads();
#pragma unroll
        for (int pass = 0; pass < 16; ++pass) {
            const int row = pass * 4 + wv;
            uint2 v;
            v.x = (unsigned int)f2bf(pf[pass].x) | ((unsigned int)f2bf(pf[pass].y) << 16);
            v.y = (unsigned int)f2bf(pf[pass].z) | ((unsigned int)f2bf(pf[pass].w) << 16);
            *(uint2*)(s_w + row * 264 + lane * 4) = v;
        }
        __syncthreads();
        if (ss < 1) FC1_LOAD(1);

        const unsigned short* arow = s_w + (wv * 16 + l15) * 264;
#pragma unroll
        for (int kk = 0; kk < 8; ++kk) {
            bf16x8 a = *(const bf16x8*)(arow + kk * 32 + lq * 8);
            const int kglob = k0 + ss * 256 + kk * 32 + lq * 8;
            const int kb = kglob >> 6, lq2 = (kglob >> 4) & 3, hi = (kglob >> 3) & 1;
            const unsigned short* bp = actB +
                ((((size_t)kb * 4 + lq2) * 2 + hi) * 64 + l15) * 8;
#pragma unroll
            for (int t = 0; t < 4; ++t) {
                bf16x8 b = *(const bf16x8*)(bp + t * 128);
                acc[t] = mfma16(a, b, acc[t]);
            }
        }
    }
#undef FC1_LOAD

    float* pbase = part + ((size_t)ks * 1024 + jt * 64 + wv * 16 + lq * 4) * 64 + l15;
#pragma unroll
    for (int t = 0; t < 4; ++t)
#pragma unroll
        for (int r = 0; r < 4; ++r)
            pbase[(size_t)r * 64 + t * 16] = acc[t][r];
}

__global__ __launch_bounds__(256) void k_fc1r(const float* __restrict__ part,
                                              const float* __restrict__ b,
                                              float* __restrict__ fc1T)
{
    int i = blockIdx.x * 256 + threadIdx.x;
    if (i >= 65536) return;
    float s = 0.0f;
    for (int ks = 0; ks < NKS; ++ks) s += part[(size_t)ks * 65536 + i];
    int j = i >> 6;
    fc1T[i] = fmaxf(s + b[j], 0.0f);
}

__global__ __launch_bounds__(256) void k_fc2(const float* __restrict__ fc1T,
                                             const float* __restrict__ w,
                                             const float* __restrict__ b,
                                             float* __restrict__ out)
{
    __shared__ float red[256];
    const int a_ = blockIdx.x;
    const int tid = threadIdx.x, lane = tid & 63, q = tid >> 6;
    float acc = 0.0f;
    const float* wr = w + (size_t)a_ * 1024;
    for (int k = q * 256; k < q * 256 + 256; ++k)
        acc = fmaf(fc1T[k * 64 + lane], wr[k], acc);
    red[tid] = acc;
    __syncthreads();
    if (q == 0) {
        float s = red[tid] + red[tid + 64] + red[tid + 128] + red[tid + 192] + b[a_];
        out[lane * 28 + a_] = s;
    }
}

extern "C" void kernel_launch(void* const* d_in, const int* in_sizes, int n_in,
                              void* d_out, int out_size, void* d_ws, size_t ws_size,
                              hipStream_t stream)
{
    const float* feats = (const float*)d_in[0];
    const int*   prog  = (const int*)d_in[1];
    char* ws  = (char*)d_ws;
    float* out = (float*)d_out;

    RepackArgs ra;
    ra.src[0]  = (const float*)d_in[2];   // stem_w1
    ra.src[1]  = (const float*)d_in[4];   // stem_w2
    ra.src[2]  = (const float*)d_in[6];   // att_w1
    ra.src[3]  = (const float*)d_in[8];   // att_w2
    ra.src[4]  = (const float*)d_in[12];  // rel_w1
    ra.src[5]  = (const float*)d_in[14];  // rel_w2
    ra.src[6]  = (const float*)d_in[16];  // rel_w3
    ra.src[7]  = (const float*)d_in[18];  // rel_w4
    ra.src[8]  = (const float*)d_in[20];  // rel_w5
    ra.src[9]  = (const float*)d_in[24];  // qry_w1
    ra.src[10] = (const float*)d_in[26];  // qry_w2
    ra.src[11] = (const float*)d_in[28];  // cls_w

    k_repack<<<dim3(64, 12), 256, 0, stream>>>(ra, ws);
    k_decode_init<<<256, 256, 0, stream>>>(prog, ws);

    // stem1: feats(f32) -> partials(8) -> XA
    k_stem1p<<<512, 512, 0, stream>>>(feats, (const unsigned short*)(ws + B_WSTEM1), ws);
    k_stem1r<<<784, 256, 0, stream>>>(ws, (const float*)d_in[3],
                                      (unsigned short*)(ws + B_XA));

    // stem2: XA -> STEM
    k_conv_stem2<<<512, 256, 0, stream>>>((const unsigned short*)(ws + B_XA),
                                          (const unsigned short*)(ws + B_WSTEM2),
                                          (const float*)d_in[5],
                                          (unsigned short*)(ws + B_STEM));

    RArgs ga;
    ga.ws = ws;
    ga.mbias[0] = (const float*)d_in[7];   // att_b1
    ga.mbias[1] = (const float*)d_in[9];   // att_b2
    ga.mbias[2] = (const float*)d_in[13];  // rel_b1
    ga.mbias[3] = (const float*)d_in[15];  // rel_b2
    ga.mbias[4] = (const float*)d_in[17];  // rel_b3
    ga.mbias[5] = (const float*)d_in[19];  // rel_b4
    ga.mbias[6] = (const float*)d_in[21];  // rel_b5
    ga.mbias[7] = (const float*)d_in[25];  // qry_b1
    ga.mbias[8] = (const float*)d_in[27];  // qry_b2
    ga.w1x1[0]  = (const float*)d_in[10];  // att_w3
    ga.w1x1[1]  = (const float*)d_in[22];  // rel_w6
    ga.b1x1[0]  = (const float*)d_in[11];  // att_b3
    ga.b1x1[1]  = (const float*)d_in[23];  // rel_b6

    for (int r = 0; r < NROUNDS; ++r)
        k_round<<<512, 256, 0, stream>>>(ga, r);

    k_cls_pool<<<1024, 256, 0, stream>>>((const unsigned short*)(ws + B_FEAT),
                                         (const unsigned short*)(ws + B_WCLS),
                                         (const float*)d_in[29],
                                         (unsigned short*)(ws + B_ACTB));
    k_fc1p<<<1568, 256, 0, stream>>>((const unsigned short*)(ws + B_ACTB),
                                     (const float*)d_in[30], (float*)(ws + B_FC1P));
    k_fc1r<<<256, 256, 0, stream>>>((const float*)(ws + B_FC1P), (const float*)d_in[31],
                                    (float*)(ws + B_FC1T));
    k_fc2<<<28, 256, 0, stream>>>((const float*)(ws + B_FC1T), (const float*)d_in[32],
                                  (const float*)d_in[33], out);
}